// Round 3
// baseline (491.104 us; speedup 1.0000x reference)
//
#include <hip/hip_runtime.h>
#include <hip/hip_bf16.h>
#include <cstdint>
#include <cstddef>

#define NN 50000
#define NE 800000
#define FD 128
#define NC 40
#define SCAN_BLOCKS ((NN + 255) / 256)   // 196

// ---------------- CSR build ----------------

__global__ void count_kernel(const int* __restrict__ dst, int* __restrict__ counts) {
  int i = blockIdx.x * blockDim.x + threadIdx.x;
  if (i < NE) atomicAdd(&counts[dst[i]], 1);
}

__global__ void norm_kernel(const int* __restrict__ counts, float* __restrict__ norm) {
  int i = blockIdx.x * blockDim.x + threadIdx.x;
  if (i < NN) norm[i] = rsqrtf((float)(counts[i] + 1));  // +1 self loop
}

__global__ void scanA_kernel(const int* __restrict__ counts, int* __restrict__ rowptr,
                             int* __restrict__ bsum) {
  __shared__ int sm[256];
  int t = threadIdx.x;
  int g = blockIdx.x * 256 + t;
  int v = (g < NN) ? counts[g] : 0;
  sm[t] = v;
  __syncthreads();
  for (int off = 1; off < 256; off <<= 1) {
    int x = (t >= off) ? sm[t - off] : 0;
    __syncthreads();
    sm[t] += x;
    __syncthreads();
  }
  if (g < NN) rowptr[g] = sm[t] - v;          // block-local exclusive
  if (t == 255) bsum[blockIdx.x] = sm[255];   // block total
}

__global__ void scanB_kernel(const int* __restrict__ bsum, int* __restrict__ boff) {
  __shared__ int sm[256];
  int t = threadIdx.x;
  int v = (t < SCAN_BLOCKS) ? bsum[t] : 0;
  sm[t] = v;
  __syncthreads();
  for (int off = 1; off < 256; off <<= 1) {
    int x = (t >= off) ? sm[t - off] : 0;
    __syncthreads();
    sm[t] += x;
    __syncthreads();
  }
  boff[t] = sm[t] - v;  // exclusive scan of block sums
}

__global__ void scanC_kernel(int* __restrict__ rowptr, int* __restrict__ wrt,
                             const int* __restrict__ boff) {
  int t = threadIdx.x;
  int g = blockIdx.x * 256 + t;
  if (g < NN) {
    int v = rowptr[g] + boff[blockIdx.x];
    rowptr[g] = v;
    wrt[g] = v;
  }
  if (g == 0) rowptr[NN] = NE;
}

__global__ void scatter_kernel(const int* __restrict__ src, const int* __restrict__ dst,
                               int* __restrict__ wrt, int* __restrict__ col) {
  int i = blockIdx.x * blockDim.x + threadIdx.x;
  if (i < NE) {
    int p = atomicAdd(&wrt[dst[i]], 1);
    col[p] = src[i];
  }
}

// ---------------- GCN aggregation (gather over CSR) ----------------
// out[i][c] = relu( norm[i]*( sum_e norm[col[e]]*h[col[e]][c] + norm[i]*h[i][c] )
//                   + bias[c] + (y1 ? y1[i][c] : 0) )
__global__ void agg_kernel(const float* __restrict__ h, const float* __restrict__ norm,
                           const int* __restrict__ rowptr, const int* __restrict__ col,
                           const float* __restrict__ bias, const float* __restrict__ y1,
                           float* __restrict__ out) {
  int i = blockIdx.x;
  int c = threadIdx.x;  // 128 threads = one feature each
  __shared__ int cols[128];
  __shared__ float ws[128];
  int beg = rowptr[i], end = rowptr[i + 1];
  float s = 0.f;
  for (int base = beg; base < end; base += 128) {
    int e = base + c;
    if (e < end) {
      int sn = col[e];
      cols[c] = sn;
      ws[c] = norm[sn];
    }
    __syncthreads();
    int cnt = min(128, end - base);
    for (int j = 0; j < cnt; ++j)
      s += ws[j] * h[(size_t)cols[j] * FD + c];
    __syncthreads();
  }
  float ni = norm[i];
  float v = ni * (s + ni * h[(size_t)i * FD + c]) + bias[c];
  if (y1) v += y1[(size_t)i * FD + c];
  out[(size_t)i * FD + c] = fmaxf(v, 0.f);
}

// ---------------- 128x128 GEMM:  out[M x 128] = X[M x 128] @ W[128 x 128] ----------------
template <int FUSE>  // 0: plain, 1: +bias +relu
__global__ __launch_bounds__(256) void gemm128_kernel(const float* __restrict__ X,
                                                      const float* __restrict__ W,
                                                      const float* __restrict__ bias,
                                                      float* __restrict__ out, int M) {
  __shared__ float Xst[32][68];   // transposed [k][row], 68 keeps float4 alignment
  __shared__ float Ws[32][128];
  int tid = threadIdx.x;
  int row0 = blockIdx.x * 64;
  int tr = tid >> 4;   // 0..15 -> rows tr*4..tr*4+3
  int tc = tid & 15;   // 0..15 -> cols tc*8..tc*8+7

  float acc[4][8];
#pragma unroll
  for (int i = 0; i < 4; i++)
#pragma unroll
    for (int j = 0; j < 8; j++) acc[i][j] = 0.f;

  for (int kt = 0; kt < 4; ++kt) {
    // stage X tile 64 rows x 32 cols (transposed into LDS)
    {
      int r = tid >> 3;            // 0..31
      int c4 = (tid & 7) * 4;      // 0..28
#pragma unroll
      for (int it = 0; it < 2; ++it) {
        int rr = r + it * 32;
        int grow = row0 + rr;
        float4 v = make_float4(0.f, 0.f, 0.f, 0.f);
        if (grow < M) v = *(const float4*)&X[(size_t)grow * FD + kt * 32 + c4];
        Xst[c4 + 0][rr] = v.x;
        Xst[c4 + 1][rr] = v.y;
        Xst[c4 + 2][rr] = v.z;
        Xst[c4 + 3][rr] = v.w;
      }
    }
    // stage W tile 32 x 128
    {
#pragma unroll
      for (int j = 0; j < 4; ++j) {
        int idx = tid + j * 256;       // 0..1023 float4s
        int k = idx >> 5;              // 0..31
        int n4 = (idx & 31) * 4;       // 0..124
        *(float4*)&Ws[k][n4] = *(const float4*)&W[(size_t)(kt * 32 + k) * FD + n4];
      }
    }
    __syncthreads();
#pragma unroll
    for (int k = 0; k < 32; ++k) {
      float4 xv = *(const float4*)&Xst[k][tr * 4];
      float4 wa = *(const float4*)&Ws[k][tc * 8];
      float4 wb = *(const float4*)&Ws[k][tc * 8 + 4];
      float xs[4] = {xv.x, xv.y, xv.z, xv.w};
      float wv[8] = {wa.x, wa.y, wa.z, wa.w, wb.x, wb.y, wb.z, wb.w};
#pragma unroll
      for (int i = 0; i < 4; i++)
#pragma unroll
        for (int j = 0; j < 8; j++) acc[i][j] = fmaf(xs[i], wv[j], acc[i][j]);
    }
    __syncthreads();
  }
#pragma unroll
  for (int i = 0; i < 4; i++) {
    int grow = row0 + tr * 4 + i;
    if (grow < M) {
#pragma unroll
      for (int jj = 0; jj < 2; jj++) {
        int cc = tc * 8 + jj * 4;
        float4 o;
        o.x = acc[i][jj * 4 + 0];
        o.y = acc[i][jj * 4 + 1];
        o.z = acc[i][jj * 4 + 2];
        o.w = acc[i][jj * 4 + 3];
        if (FUSE) {
          const float4 bv = *(const float4*)&bias[cc];
          o.x = fmaxf(o.x + bv.x, 0.f);
          o.y = fmaxf(o.y + bv.y, 0.f);
          o.z = fmaxf(o.z + bv.z, 0.f);
          o.w = fmaxf(o.w + bv.w, 0.f);
        }
        *(float4*)&out[(size_t)grow * FD + cc] = o;
      }
    }
  }
}

// ---------------- fc3 (128 -> 40) + log_softmax ----------------
__global__ void fc3_kernel(const float* __restrict__ Y, const float* __restrict__ W,
                           const float* __restrict__ b, float* __restrict__ out) {
  int i = blockIdx.x;
  int t = threadIdx.x;  // 64 = one wave
  __shared__ float row[128];
  row[t] = Y[(size_t)i * FD + t];
  row[t + 64] = Y[(size_t)i * FD + 64 + t];
  __syncthreads();
  float v = -1e30f;
  if (t < NC) {
    v = b[t];
#pragma unroll 8
    for (int k = 0; k < FD; ++k) v = fmaf(row[k], W[k * NC + t], v);
  }
  float m = v;
  for (int off = 32; off; off >>= 1) m = fmaxf(m, __shfl_down(m, off));
  m = __shfl(m, 0);
  float ex = (t < NC) ? expf(v - m) : 0.f;
  float s2 = ex;
  for (int off = 32; off; off >>= 1) s2 += __shfl_down(s2, off);
  s2 = __shfl(s2, 0);
  if (t < NC) out[(size_t)i * NC + t] = v - m - logf(s2);
}

// ---------------- launch ----------------

extern "C" void kernel_launch(void* const* d_in, const int* in_sizes, int n_in,
                              void* d_out, int out_size, void* d_ws, size_t ws_size,
                              hipStream_t stream) {
  const float* x = (const float*)d_in[0];
  const float* Wconv = (const float*)d_in[1];   // [3][128][128]
  const float* bconv = (const float*)d_in[2];   // [3][128]
  const float* fc1_w = (const float*)d_in[3];
  const float* fc1_b = (const float*)d_in[4];
  const float* fc2_w = (const float*)d_in[5];
  const float* fc2_b = (const float*)d_in[6];
  const float* fc3_w = (const float*)d_in[7];
  const float* fc3_b = (const float*)d_in[8];
  const int* edge = (const int*)d_in[9];
  const int* esrc = edge;
  const int* edst = edge + NE;

  uint8_t* w = (uint8_t*)d_ws;
  size_t off = 0;
  auto take = [&](size_t bytes) -> void* {
    void* p = w + off;
    off += (bytes + 255) & ~(size_t)255;
    return p;
  };
  float* norm = (float*)take((size_t)NN * 4);
  int* counts = (int*)take((size_t)NN * 4);
  int* rowptr = (int*)take((size_t)(NN + 1) * 4);
  int* wrt = (int*)take((size_t)NN * 4);
  int* bsum = (int*)take(256 * 4);
  int* boff = (int*)take(256 * 4);
  int* col = (int*)take((size_t)NE * 4);
  float* h = (float*)take((size_t)NN * FD * 4);
  float* y = (float*)take((size_t)NN * FD * 4);
  float* y1 = (float*)take((size_t)NN * FD * 4);

  hipMemsetAsync(counts, 0, (size_t)NN * 4, stream);

  count_kernel<<<(NE + 255) / 256, 256, 0, stream>>>(edst, counts);
  norm_kernel<<<(NN + 255) / 256, 256, 0, stream>>>(counts, norm);
  scanA_kernel<<<SCAN_BLOCKS, 256, 0, stream>>>(counts, rowptr, bsum);
  scanB_kernel<<<1, 256, 0, stream>>>(bsum, boff);
  scanC_kernel<<<SCAN_BLOCKS, 256, 0, stream>>>(rowptr, wrt, boff);
  scatter_kernel<<<(NE + 255) / 256, 256, 0, stream>>>(esrc, edst, wrt, col);

  const int GB = (NN + 63) / 64;  // gemm blocks

  // layer 1
  gemm128_kernel<0><<<GB, 256, 0, stream>>>(x, Wconv, nullptr, h, NN);
  agg_kernel<<<NN, 128, 0, stream>>>(h, norm, rowptr, col, bconv, nullptr, y1);
  // layer 2
  gemm128_kernel<0><<<GB, 256, 0, stream>>>(y1, Wconv + 16384, nullptr, h, NN);
  agg_kernel<<<NN, 128, 0, stream>>>(h, norm, rowptr, col, bconv + FD, y1, y);
  // layer 3
  gemm128_kernel<0><<<GB, 256, 0, stream>>>(y, Wconv + 2 * 16384, nullptr, h, NN);
  agg_kernel<<<NN, 128, 0, stream>>>(h, norm, rowptr, col, bconv + 2 * FD, y1, y);

  // fc1, fc2 (bias+relu fused)
  gemm128_kernel<1><<<GB, 256, 0, stream>>>(y, fc1_w, fc1_b, h, NN);
  gemm128_kernel<1><<<GB, 256, 0, stream>>>(h, fc2_w, fc2_b, y, NN);

  // fc3 + log_softmax
  fc3_kernel<<<NN, 64, 0, stream>>>(y, fc3_w, fc3_b, (float*)d_out);
}

// Round 5
// 361.237 us; speedup vs baseline: 1.3595x; 1.3595x over previous
//
#include <hip/hip_runtime.h>
#include <hip/hip_bf16.h>
#include <cstdint>
#include <cstddef>

#define NN 50000
#define NE 800000
#define FD 128
#define NC 40
#define SCAN_BLOCKS ((NN + 255) / 256)   // 196

typedef unsigned short u16;
typedef short s16x8 __attribute__((ext_vector_type(8)));
typedef float f32x4 __attribute__((ext_vector_type(4)));

__device__ __forceinline__ float b2f(short h) {
  return __uint_as_float(((unsigned int)(u16)h) << 16);
}
__device__ __forceinline__ u16 f2b(float f) {
  unsigned int u = __float_as_uint(f);
  return (u16)((u + 0x7FFFu + ((u >> 16) & 1u)) >> 16);
}

// ---------------- CSR build ----------------

__global__ void count_kernel(const int* __restrict__ dst, int* __restrict__ counts) {
  int i = blockIdx.x * blockDim.x + threadIdx.x;
  if (i < NE) atomicAdd(&counts[dst[i]], 1);
}

__global__ void norm_kernel(const int* __restrict__ counts, float* __restrict__ norm) {
  int i = blockIdx.x * blockDim.x + threadIdx.x;
  if (i < NN) norm[i] = rsqrtf((float)(counts[i] + 1));  // +1 self loop
}

__global__ void scanA_kernel(const int* __restrict__ counts, int* __restrict__ rowptr,
                             int* __restrict__ bsum) {
  __shared__ int sm[256];
  int t = threadIdx.x;
  int g = blockIdx.x * 256 + t;
  int v = (g < NN) ? counts[g] : 0;
  sm[t] = v;
  __syncthreads();
  for (int off = 1; off < 256; off <<= 1) {
    int x = (t >= off) ? sm[t - off] : 0;
    __syncthreads();
    sm[t] += x;
    __syncthreads();
  }
  if (g < NN) rowptr[g] = sm[t] - v;
  if (t == 255) bsum[blockIdx.x] = sm[255];
}

__global__ void scanB_kernel(const int* __restrict__ bsum, int* __restrict__ boff) {
  __shared__ int sm[256];
  int t = threadIdx.x;
  int v = (t < SCAN_BLOCKS) ? bsum[t] : 0;
  sm[t] = v;
  __syncthreads();
  for (int off = 1; off < 256; off <<= 1) {
    int x = (t >= off) ? sm[t - off] : 0;
    __syncthreads();
    sm[t] += x;
    __syncthreads();
  }
  boff[t] = sm[t] - v;
}

__global__ void scanC_kernel(int* __restrict__ rowptr, int* __restrict__ wrt,
                             const int* __restrict__ boff) {
  int t = threadIdx.x;
  int g = blockIdx.x * 256 + t;
  if (g < NN) {
    int v = rowptr[g] + boff[blockIdx.x];
    rowptr[g] = v;
    wrt[g] = v;
  }
  if (g == 0) rowptr[NN] = NE;
}

__global__ void scatter_kernel(const int* __restrict__ src, const int* __restrict__ dst,
                               int* __restrict__ wrt, int* __restrict__ col) {
  int i = blockIdx.x * blockDim.x + threadIdx.x;
  if (i < NE) {
    int p = atomicAdd(&wrt[dst[i]], 1);
    col[p] = src[i];
  }
}

// ---------------- prep: fp32 -> bf16 convert / weight transpose ----------------

__global__ void convx_kernel(const float* __restrict__ x, u16* __restrict__ xb) {
  const int total = NN * FD / 4;
  for (int i = blockIdx.x * blockDim.x + threadIdx.x; i < total; i += gridDim.x * blockDim.x) {
    float4 v = *(const float4*)&x[(size_t)i * 4];
    u16 o0 = f2b(v.x), o1 = f2b(v.y), o2 = f2b(v.z), o3 = f2b(v.w);
    u16* p = xb + (size_t)i * 4;
    p[0] = o0; p[1] = o1; p[2] = o2; p[3] = o3;
  }
}

// Wt[mat][n][k] = bf16(W[mat][k][n]); mat 5 = fc3 padded to 48 rows
__global__ void transw_kernel(const float* __restrict__ Wconv, const float* __restrict__ fc1_w,
                              const float* __restrict__ fc2_w, const float* __restrict__ fc3_w,
                              u16* __restrict__ Wt, u16* __restrict__ W3t) {
  int mat = blockIdx.y;
  int idx = blockIdx.x * 256 + threadIdx.x;  // 0..16383
  if (mat < 5) {
    int n = idx >> 7, k = idx & 127;
    const float* W = (mat < 3) ? (Wconv + (size_t)mat * FD * FD) : ((mat == 3) ? fc1_w : fc2_w);
    Wt[(size_t)mat * FD * FD + n * FD + k] = f2b(W[k * FD + n]);
  } else {
    if (idx < 48 * FD) {
      int n = idx >> 7, k = idx & 127;
      W3t[n * FD + k] = (n < NC) ? f2b(fc3_w[k * NC + n]) : (u16)0;
    }
  }
}

// ---------------- bf16 MFMA GEMM: out[M x 128] = X[M x 128] @ W, W given as Wt[n][k] ----------------
template <int FUSE>  // 1: +bias +relu
__global__ __launch_bounds__(256) void mfma_gemm(const u16* __restrict__ X,
                                                 const u16* __restrict__ Wt,
                                                 const float* __restrict__ bias,
                                                 u16* __restrict__ out, int M) {
  int wid = threadIdx.x >> 6;
  int lane = threadIdx.x & 63;
  int g = lane >> 4, c = lane & 15;
  int mbase = blockIdx.x * 64 + wid * 16;

  int arow = mbase + c;
  if (arow > M - 1) arow = M - 1;             // clamp; corrupted rows are masked at store
  const u16* aptr = X + (size_t)arow * FD + g * 8;
  const u16* bptr = Wt + (size_t)c * FD + g * 8;

  f32x4 acc[8];
#pragma unroll
  for (int n = 0; n < 8; ++n) acc[n] = (f32x4)(0.f);

#pragma unroll
  for (int ks = 0; ks < 4; ++ks) {
    s16x8 a = *(const s16x8*)(aptr + ks * 32);
#pragma unroll
    for (int n = 0; n < 8; ++n) {
      s16x8 b = *(const s16x8*)(bptr + ks * 32 + n * 16 * FD);
      acc[n] = __builtin_amdgcn_mfma_f32_16x16x32_bf16(a, b, acc[n], 0, 0, 0);
    }
  }

  int orow = mbase + 4 * g;
#pragma unroll
  for (int n = 0; n < 8; ++n) {
#pragma unroll
    for (int r = 0; r < 4; ++r) {
      int rr = orow + r;
      if (rr < M) {
        float v = acc[n][r];
        if (FUSE) v = fmaxf(v + bias[n * 16 + c], 0.f);
        out[(size_t)rr * FD + n * 16 + c] = f2b(v);
      }
    }
  }
}

// ---------------- GCN aggregation: one wave per node, bf16 rows ----------------
// out[i][:] = relu( ni*( sum_e norm[col[e]]*h[col[e]][:] + ni*h[i][:] ) + bias + (y1?) )
__global__ __launch_bounds__(256) void agg_bf16(const u16* __restrict__ h,
                                                const float* __restrict__ norm,
                                                const int* __restrict__ rowptr,
                                                const int* __restrict__ col,
                                                const float* __restrict__ bias,
                                                const u16* __restrict__ y1,
                                                u16* __restrict__ out) {
  int wid = threadIdx.x >> 6;
  int lane = threadIdx.x & 63;
  int i = blockIdx.x * 4 + wid;
  if (i >= NN) return;
  int g = lane >> 4, c = lane & 15;  // group g handles edge slot g; lane covers cols c*8..c*8+7

  float acc[8];
#pragma unroll
  for (int j = 0; j < 8; ++j) acc[j] = 0.f;

  int beg = rowptr[i], end = rowptr[i + 1];
  for (int e0 = beg; e0 < end; e0 += 4) {
    int e = e0 + g;
    if (e < end) {
      int sn = col[e];
      float w = norm[sn];
      s16x8 row = *(const s16x8*)(h + (size_t)sn * FD + c * 8);
#pragma unroll
      for (int j = 0; j < 8; ++j) acc[j] = fmaf(w, b2f(row[j]), acc[j]);
    }
  }
#pragma unroll
  for (int j = 0; j < 8; ++j) {
    acc[j] += __shfl_xor(acc[j], 16);
    acc[j] += __shfl_xor(acc[j], 32);
  }
  if (g == 0) {
    float ni = norm[i];
    s16x8 self = *(const s16x8*)(h + (size_t)i * FD + c * 8);
    s16x8 res;
    if (y1) res = *(const s16x8*)(y1 + (size_t)i * FD + c * 8);
    u16 pk[8];
#pragma unroll
    for (int j = 0; j < 8; ++j) {
      float v = ni * (acc[j] + ni * b2f(self[j])) + bias[c * 8 + j];
      if (y1) v += b2f(res[j]);
      pk[j] = f2b(fmaxf(v, 0.f));
    }
    u16* po = out + (size_t)i * FD + c * 8;
#pragma unroll
    for (int j = 0; j < 8; ++j) po[j] = pk[j];
  }
}

// ---------------- fc3 (128 -> 40, padded 48) + log_softmax, MFMA ----------------
__global__ __launch_bounds__(256) void fc3_mfma(const u16* __restrict__ X,
                                                const u16* __restrict__ W3t,
                                                const float* __restrict__ b3,
                                                float* __restrict__ out, int M) {
  int wid = threadIdx.x >> 6;
  int lane = threadIdx.x & 63;
  int g = lane >> 4, c = lane & 15;
  int mbase = blockIdx.x * 64 + wid * 16;

  int arow = mbase + c;
  if (arow > M - 1) arow = M - 1;
  const u16* aptr = X + (size_t)arow * FD + g * 8;
  const u16* bptr = W3t + (size_t)c * FD + g * 8;

  f32x4 acc[3];
#pragma unroll
  for (int n = 0; n < 3; ++n) acc[n] = (f32x4)(0.f);

#pragma unroll
  for (int ks = 0; ks < 4; ++ks) {
    s16x8 a = *(const s16x8*)(aptr + ks * 32);
#pragma unroll
    for (int n = 0; n < 3; ++n) {
      s16x8 b = *(const s16x8*)(bptr + ks * 32 + n * 16 * FD);
      acc[n] = __builtin_amdgcn_mfma_f32_16x16x32_bf16(a, b, acc[n], 0, 0, 0);
    }
  }

  int row0 = mbase + 4 * g;
#pragma unroll
  for (int r = 0; r < 4; ++r) {
    float v0 = acc[0][r] + b3[c];
    float v1 = acc[1][r] + b3[16 + c];
    float v2 = (c < 8) ? (acc[2][r] + b3[32 + c]) : -1e30f;
    float m = fmaxf(fmaxf(v0, v1), v2);
#pragma unroll
    for (int off = 1; off <= 8; off <<= 1) m = fmaxf(m, __shfl_xor(m, off));
    float s = __expf(v0 - m) + __expf(v1 - m) + ((c < 8) ? __expf(v2 - m) : 0.f);
#pragma unroll
    for (int off = 1; off <= 8; off <<= 1) s += __shfl_xor(s, off);
    float lse = m + __logf(s);
    int rr = row0 + r;
    if (rr < M) {
      out[(size_t)rr * NC + c] = v0 - lse;
      out[(size_t)rr * NC + 16 + c] = v1 - lse;
      if (c < 8) out[(size_t)rr * NC + 32 + c] = v2 - lse;
    }
  }
}

// ---------------- launch ----------------

extern "C" void kernel_launch(void* const* d_in, const int* in_sizes, int n_in,
                              void* d_out, int out_size, void* d_ws, size_t ws_size,
                              hipStream_t stream) {
  const float* x = (const float*)d_in[0];
  const float* Wconv = (const float*)d_in[1];
  const float* bconv = (const float*)d_in[2];
  const float* fc1_w = (const float*)d_in[3];
  const float* fc1_b = (const float*)d_in[4];
  const float* fc2_w = (const float*)d_in[5];
  const float* fc2_b = (const float*)d_in[6];
  const float* fc3_w = (const float*)d_in[7];
  const float* fc3_b = (const float*)d_in[8];
  const int* edge = (const int*)d_in[9];
  const int* esrc = edge;
  const int* edst = edge + NE;

  uint8_t* w = (uint8_t*)d_ws;
  size_t off = 0;
  auto take = [&](size_t bytes) -> void* {
    void* p = w + off;
    off += (bytes + 255) & ~(size_t)255;
    return p;
  };
  float* norm = (float*)take((size_t)NN * 4);
  int* counts = (int*)take((size_t)NN * 4);
  int* rowptr = (int*)take((size_t)(NN + 1) * 4);
  int* wrt = (int*)take((size_t)NN * 4);
  int* bsum = (int*)take(256 * 4);
  int* boff = (int*)take(256 * 4);
  int* col = (int*)take((size_t)NE * 4);
  u16* Wt = (u16*)take((size_t)5 * FD * FD * 2);
  u16* W3t = (u16*)take((size_t)48 * FD * 2);
  u16* xb = (u16*)take((size_t)NN * FD * 2);
  u16* h = (u16*)take((size_t)NN * FD * 2);
  u16* y = (u16*)take((size_t)NN * FD * 2);
  u16* y1 = (u16*)take((size_t)NN * FD * 2);

  hipMemsetAsync(counts, 0, (size_t)NN * 4, stream);

  count_kernel<<<(NE + 255) / 256, 256, 0, stream>>>(edst, counts);
  norm_kernel<<<(NN + 255) / 256, 256, 0, stream>>>(counts, norm);
  scanA_kernel<<<SCAN_BLOCKS, 256, 0, stream>>>(counts, rowptr, bsum);
  scanB_kernel<<<1, 256, 0, stream>>>(bsum, boff);
  scanC_kernel<<<SCAN_BLOCKS, 256, 0, stream>>>(rowptr, wrt, boff);
  scatter_kernel<<<(NE + 255) / 256, 256, 0, stream>>>(esrc, edst, wrt, col);

  convx_kernel<<<2048, 256, 0, stream>>>(x, xb);
  transw_kernel<<<dim3(64, 6), 256, 0, stream>>>(Wconv, fc1_w, fc2_w, fc3_w, Wt, W3t);

  const int GB = (NN + 63) / 64;  // 782

  // conv layer 1
  mfma_gemm<0><<<GB, 256, 0, stream>>>(xb, Wt, nullptr, h, NN);
  agg_bf16<<<(NN + 3) / 4, 256, 0, stream>>>(h, norm, rowptr, col, bconv, nullptr, y1);
  // conv layer 2
  mfma_gemm<0><<<GB, 256, 0, stream>>>(y1, Wt + FD * FD, nullptr, h, NN);
  agg_bf16<<<(NN + 3) / 4, 256, 0, stream>>>(h, norm, rowptr, col, bconv + FD, y1, y);
  // conv layer 3
  mfma_gemm<0><<<GB, 256, 0, stream>>>(y, Wt + 2 * FD * FD, nullptr, h, NN);
  agg_bf16<<<(NN + 3) / 4, 256, 0, stream>>>(h, norm, rowptr, col, bconv + 2 * FD, y1, xb);

  // fc1, fc2 (bias+relu fused)
  mfma_gemm<1><<<GB, 256, 0, stream>>>(xb, Wt + 3 * FD * FD, fc1_b, h, NN);
  mfma_gemm<1><<<GB, 256, 0, stream>>>(h, Wt + 4 * FD * FD, fc2_b, y, NN);

  // fc3 + log_softmax
  fc3_mfma<<<GB, 256, 0, stream>>>(y, W3t, fc3_b, (float*)d_out, NN);
}

// Round 6
// 285.180 us; speedup vs baseline: 1.7221x; 1.2667x over previous
//
#include <hip/hip_runtime.h>
#include <hip/hip_bf16.h>
#include <cstdint>
#include <cstddef>

#define NN 50000
#define NE 800000
#define FD 128
#define NC 40

#define NBKT 128
#define BSHIFT 9                      // 512 nodes per bucket
#define BNODES 512
#define BCAP 10240                    // bucket capacity (mean ~8192, +20 sigma)
#define CHUNK 8192
#define PA_BLOCKS ((NE + CHUNK - 1) / CHUNK)   // 98

typedef unsigned short u16;
typedef short s16x8 __attribute__((ext_vector_type(8)));
typedef float f32x4 __attribute__((ext_vector_type(4)));

__device__ __forceinline__ float b2f(short h) {
  return __uint_as_float(((unsigned int)(u16)h) << 16);
}
__device__ __forceinline__ u16 f2b(float f) {
  unsigned int u = __float_as_uint(f);
  return (u16)((u + 0x7FFFu + ((u >> 16) & 1u)) >> 16);
}

// ---------------- CSR build: 2-phase LDS binning ----------------

// Phase A: bin edges into 128 buckets by dst>>9. Per block: LDS histogram,
// one global atomic per (block,bucket) to reserve a contiguous run, then place.
__global__ __launch_bounds__(256) void binA_kernel(const int* __restrict__ esrc,
                                                   const int* __restrict__ edst,
                                                   int* __restrict__ bcur,
                                                   uint2* __restrict__ pairs) {
  __shared__ int lh[NBKT], gbase[NBKT], lcur[NBKT];
  int t = threadIdx.x;
  int e0 = blockIdx.x * CHUNK;
  int e1 = min(e0 + CHUNK, NE);
  for (int i = t; i < NBKT; i += 256) lh[i] = 0;
  __syncthreads();
  for (int e = e0 + t; e < e1; e += 256) {
    atomicAdd(&lh[edst[e] >> BSHIFT], 1);
  }
  __syncthreads();
  for (int i = t; i < NBKT; i += 256) {
    int c = lh[i];
    gbase[i] = (c > 0) ? atomicAdd(&bcur[i], c) : 0;
    lcur[i] = 0;
  }
  __syncthreads();
  for (int e = e0 + t; e < e1; e += 256) {
    int d = edst[e], s = esrc[e];
    int b = d >> BSHIFT;
    int r = atomicAdd(&lcur[b], 1);
    pairs[(size_t)b * BCAP + gbase[b] + r] = make_uint2((unsigned)d, (unsigned)s);
  }
}

// Exclusive scan of bucket totals -> col-space base per bucket.
__global__ void scanBkt_kernel(const int* __restrict__ bcur, int* __restrict__ cbase,
                               int* __restrict__ rowptr) {
  __shared__ int sm[NBKT];
  int t = threadIdx.x;  // NBKT threads
  int v = bcur[t];
  sm[t] = v;
  __syncthreads();
  for (int o = 1; o < NBKT; o <<= 1) {
    int x = (t >= o) ? sm[t - o] : 0;
    __syncthreads();
    sm[t] += x;
    __syncthreads();
  }
  cbase[t] = sm[t] - v;
  if (t == NBKT - 1) rowptr[NN] = NE;
}

// Phase B: per bucket: LDS histogram over 512 nodes, LDS scan, write rowptr/norm,
// place col into the bucket's contiguous window (LDS cursors only).
__global__ __launch_bounds__(256) void binB_kernel(const int* __restrict__ bcur,
                                                   const int* __restrict__ cbase,
                                                   const uint2* __restrict__ pairs,
                                                   int* __restrict__ rowptr,
                                                   float* __restrict__ normv,
                                                   int* __restrict__ col) {
  __shared__ int hist[BNODES], offs[BNODES];
  __shared__ int ws2[256];
  int b = blockIdx.x, t = threadIdx.x;
  int n0 = b << BSHIFT;
  if (n0 >= NN) return;  // empty high buckets (uniform exit, no barrier crossed)
  int nb = bcur[b];
  int base = cbase[b];
  for (int i = t; i < BNODES; i += 256) hist[i] = 0;
  __syncthreads();
  const uint2* bp = pairs + (size_t)b * BCAP;
  for (int e = t; e < nb; e += 256) {
    atomicAdd(&hist[(int)bp[e].x - n0], 1);
  }
  __syncthreads();
  int a0 = hist[2 * t], a1 = hist[2 * t + 1];
  int ps = a0 + a1;
  ws2[t] = ps;
  __syncthreads();
  for (int o = 1; o < 256; o <<= 1) {
    int v = (t >= o) ? ws2[t - o] : 0;
    __syncthreads();
    ws2[t] += v;
    __syncthreads();
  }
  int ex = ws2[t] - ps;
  offs[2 * t] = ex;
  offs[2 * t + 1] = ex + a0;
  __syncthreads();
  for (int i = t; i < BNODES; i += 256) {
    int node = n0 + i;
    if (node < NN) {
      rowptr[node] = base + offs[i];
      normv[node] = rsqrtf((float)(hist[i] + 1));  // +1 self loop
    }
  }
  __syncthreads();
  for (int e = t; e < nb; e += 256) {
    uint2 p = bp[e];
    int pos = atomicAdd(&offs[(int)p.x - n0], 1);
    col[base + pos] = (int)p.y;
  }
}

// ---------------- prep: fp32 -> bf16 convert / weight transpose ----------------

__global__ void convx_kernel(const float* __restrict__ x, u16* __restrict__ xb) {
  const int total = NN * FD / 4;
  for (int i = blockIdx.x * blockDim.x + threadIdx.x; i < total; i += gridDim.x * blockDim.x) {
    float4 v = *(const float4*)&x[(size_t)i * 4];
    u16 o0 = f2b(v.x), o1 = f2b(v.y), o2 = f2b(v.z), o3 = f2b(v.w);
    u16* p = xb + (size_t)i * 4;
    p[0] = o0; p[1] = o1; p[2] = o2; p[3] = o3;
  }
}

// Wt[mat][n][k] = bf16(W[mat][k][n]); mat 5 = fc3 padded to 48 rows
__global__ void transw_kernel(const float* __restrict__ Wconv, const float* __restrict__ fc1_w,
                              const float* __restrict__ fc2_w, const float* __restrict__ fc3_w,
                              u16* __restrict__ Wt, u16* __restrict__ W3t) {
  int mat = blockIdx.y;
  int idx = blockIdx.x * 256 + threadIdx.x;
  if (mat < 5) {
    int n = idx >> 7, k = idx & 127;
    const float* W = (mat < 3) ? (Wconv + (size_t)mat * FD * FD) : ((mat == 3) ? fc1_w : fc2_w);
    Wt[(size_t)mat * FD * FD + n * FD + k] = f2b(W[k * FD + n]);
  } else {
    if (idx < 48 * FD) {
      int n = idx >> 7, k = idx & 127;
      W3t[n * FD + k] = (n < NC) ? f2b(fc3_w[k * NC + n]) : (u16)0;
    }
  }
}

// ---------------- bf16 MFMA GEMM: out[M x 128] = X[M x 128] @ W (Wt[n][k]) ----------------
template <int FUSE>
__global__ __launch_bounds__(256) void mfma_gemm(const u16* __restrict__ X,
                                                 const u16* __restrict__ Wt,
                                                 const float* __restrict__ bias,
                                                 u16* __restrict__ out, int M) {
  int wid = threadIdx.x >> 6;
  int lane = threadIdx.x & 63;
  int g = lane >> 4, c = lane & 15;
  int mbase = blockIdx.x * 64 + wid * 16;

  int arow = mbase + c;
  if (arow > M - 1) arow = M - 1;
  const u16* aptr = X + (size_t)arow * FD + g * 8;
  const u16* bptr = Wt + (size_t)c * FD + g * 8;

  f32x4 acc[8];
#pragma unroll
  for (int n = 0; n < 8; ++n) acc[n] = (f32x4)(0.f);

#pragma unroll
  for (int ks = 0; ks < 4; ++ks) {
    s16x8 a = *(const s16x8*)(aptr + ks * 32);
#pragma unroll
    for (int n = 0; n < 8; ++n) {
      s16x8 b = *(const s16x8*)(bptr + ks * 32 + n * 16 * FD);
      acc[n] = __builtin_amdgcn_mfma_f32_16x16x32_bf16(a, b, acc[n], 0, 0, 0);
    }
  }

  int orow = mbase + 4 * g;
#pragma unroll
  for (int n = 0; n < 8; ++n) {
#pragma unroll
    for (int r = 0; r < 4; ++r) {
      int rr = orow + r;
      if (rr < M) {
        float v = acc[n][r];
        if (FUSE) v = fmaxf(v + bias[n * 16 + c], 0.f);
        out[(size_t)rr * FD + n * 16 + c] = f2b(v);
      }
    }
  }
}

// ---------------- GCN aggregation: one wave per node, bf16 rows ----------------
__global__ __launch_bounds__(256) void agg_bf16(const u16* __restrict__ h,
                                                const float* __restrict__ norm,
                                                const int* __restrict__ rowptr,
                                                const int* __restrict__ col,
                                                const float* __restrict__ bias,
                                                const u16* __restrict__ y1,
                                                u16* __restrict__ out) {
  int wid = threadIdx.x >> 6;
  int lane = threadIdx.x & 63;
  int i = blockIdx.x * 4 + wid;
  if (i >= NN) return;
  int g = lane >> 4, c = lane & 15;

  float acc[8];
#pragma unroll
  for (int j = 0; j < 8; ++j) acc[j] = 0.f;

  int beg = rowptr[i], end = rowptr[i + 1];
  for (int e0 = beg; e0 < end; e0 += 4) {
    int e = e0 + g;
    if (e < end) {
      int sn = col[e];
      float w = norm[sn];
      s16x8 row = *(const s16x8*)(h + (size_t)sn * FD + c * 8);
#pragma unroll
      for (int j = 0; j < 8; ++j) acc[j] = fmaf(w, b2f(row[j]), acc[j]);
    }
  }
#pragma unroll
  for (int j = 0; j < 8; ++j) {
    acc[j] += __shfl_xor(acc[j], 16);
    acc[j] += __shfl_xor(acc[j], 32);
  }
  if (g == 0) {
    float ni = norm[i];
    s16x8 self = *(const s16x8*)(h + (size_t)i * FD + c * 8);
    s16x8 res;
    if (y1) res = *(const s16x8*)(y1 + (size_t)i * FD + c * 8);
    u16 pk[8];
#pragma unroll
    for (int j = 0; j < 8; ++j) {
      float v = ni * (acc[j] + ni * b2f(self[j])) + bias[c * 8 + j];
      if (y1) v += b2f(res[j]);
      pk[j] = f2b(fmaxf(v, 0.f));
    }
    u16* po = out + (size_t)i * FD + c * 8;
#pragma unroll
    for (int j = 0; j < 8; ++j) po[j] = pk[j];
  }
}

// ---------------- fused fc1+fc2+fc3+log_softmax ----------------
// Each wave owns 16 rows; intermediate 16x128 tiles round-trip through a
// wave-private LDS buffer (no barriers needed: producer == consumer wave).
__global__ __launch_bounds__(256) void fc123_kernel(const u16* __restrict__ X,
                                                    const u16* __restrict__ Wt1,
                                                    const u16* __restrict__ Wt2,
                                                    const u16* __restrict__ W3t,
                                                    const float* __restrict__ b1,
                                                    const float* __restrict__ b2,
                                                    const float* __restrict__ b3,
                                                    float* __restrict__ out, int M) {
  __shared__ u16 tile[4][16][136];  // pitch 136 u16 = 272B (16B-aligned rows)
  int wid = threadIdx.x >> 6;
  int lane = threadIdx.x & 63;
  int g = lane >> 4, c = lane & 15;
  int mbase = blockIdx.x * 64 + wid * 16;

  int arow = mbase + c;
  if (arow > M - 1) arow = M - 1;
  s16x8 a[4];
#pragma unroll
  for (int ks = 0; ks < 4; ++ks)
    a[ks] = *(const s16x8*)(X + (size_t)arow * FD + ks * 32 + g * 8);

  // ---- fc1 ----
  {
    const u16* bptr = Wt1 + (size_t)c * FD + g * 8;
    f32x4 acc[8];
#pragma unroll
    for (int n = 0; n < 8; ++n) acc[n] = (f32x4)(0.f);
#pragma unroll
    for (int ks = 0; ks < 4; ++ks)
#pragma unroll
      for (int n = 0; n < 8; ++n)
        acc[n] = __builtin_amdgcn_mfma_f32_16x16x32_bf16(
            a[ks], *(const s16x8*)(bptr + ks * 32 + n * 16 * FD), acc[n], 0, 0, 0);
#pragma unroll
    for (int n = 0; n < 8; ++n)
#pragma unroll
      for (int r = 0; r < 4; ++r)
        tile[wid][4 * g + r][n * 16 + c] = f2b(fmaxf(acc[n][r] + b1[n * 16 + c], 0.f));
#pragma unroll
    for (int ks = 0; ks < 4; ++ks)
      a[ks] = *(const s16x8*)&tile[wid][c][ks * 32 + g * 8];
  }
  // ---- fc2 ----
  {
    const u16* bptr = Wt2 + (size_t)c * FD + g * 8;
    f32x4 acc[8];
#pragma unroll
    for (int n = 0; n < 8; ++n) acc[n] = (f32x4)(0.f);
#pragma unroll
    for (int ks = 0; ks < 4; ++ks)
#pragma unroll
      for (int n = 0; n < 8; ++n)
        acc[n] = __builtin_amdgcn_mfma_f32_16x16x32_bf16(
            a[ks], *(const s16x8*)(bptr + ks * 32 + n * 16 * FD), acc[n], 0, 0, 0);
#pragma unroll
    for (int n = 0; n < 8; ++n)
#pragma unroll
      for (int r = 0; r < 4; ++r)
        tile[wid][4 * g + r][n * 16 + c] = f2b(fmaxf(acc[n][r] + b2[n * 16 + c], 0.f));
#pragma unroll
    for (int ks = 0; ks < 4; ++ks)
      a[ks] = *(const s16x8*)&tile[wid][c][ks * 32 + g * 8];
  }
  // ---- fc3 (40 cols padded to 48) + log_softmax ----
  {
    const u16* bptr = W3t + (size_t)c * FD + g * 8;
    f32x4 acc[3];
#pragma unroll
    for (int n = 0; n < 3; ++n) acc[n] = (f32x4)(0.f);
#pragma unroll
    for (int ks = 0; ks < 4; ++ks)
#pragma unroll
      for (int n = 0; n < 3; ++n)
        acc[n] = __builtin_amdgcn_mfma_f32_16x16x32_bf16(
            a[ks], *(const s16x8*)(bptr + ks * 32 + n * 16 * FD), acc[n], 0, 0, 0);

    int row0 = mbase + 4 * g;
#pragma unroll
    for (int r = 0; r < 4; ++r) {
      float v0 = acc[0][r] + b3[c];
      float v1 = acc[1][r] + b3[16 + c];
      float v2 = (c < 8) ? (acc[2][r] + b3[32 + c]) : -1e30f;
      float m = fmaxf(fmaxf(v0, v1), v2);
#pragma unroll
      for (int off = 1; off <= 8; off <<= 1) m = fmaxf(m, __shfl_xor(m, off));
      float s = __expf(v0 - m) + __expf(v1 - m) + ((c < 8) ? __expf(v2 - m) : 0.f);
#pragma unroll
      for (int off = 1; off <= 8; off <<= 1) s += __shfl_xor(s, off);
      float lse = m + __logf(s);
      int rr = row0 + r;
      if (rr < M) {
        out[(size_t)rr * NC + c] = v0 - lse;
        out[(size_t)rr * NC + 16 + c] = v1 - lse;
        if (c < 8) out[(size_t)rr * NC + 32 + c] = v2 - lse;
      }
    }
  }
}

// ---------------- launch ----------------

extern "C" void kernel_launch(void* const* d_in, const int* in_sizes, int n_in,
                              void* d_out, int out_size, void* d_ws, size_t ws_size,
                              hipStream_t stream) {
  const float* x = (const float*)d_in[0];
  const float* Wconv = (const float*)d_in[1];
  const float* bconv = (const float*)d_in[2];
  const float* fc1_w = (const float*)d_in[3];
  const float* fc1_b = (const float*)d_in[4];
  const float* fc2_w = (const float*)d_in[5];
  const float* fc2_b = (const float*)d_in[6];
  const float* fc3_w = (const float*)d_in[7];
  const float* fc3_b = (const float*)d_in[8];
  const int* edge = (const int*)d_in[9];
  const int* esrc = edge;
  const int* edst = edge + NE;

  uint8_t* w = (uint8_t*)d_ws;
  size_t off = 0;
  auto take = [&](size_t bytes) -> void* {
    void* p = w + off;
    off += (bytes + 255) & ~(size_t)255;
    return p;
  };
  float* norm = (float*)take((size_t)NN * 4);
  int* rowptr = (int*)take((size_t)(NN + 1) * 4);
  int* bcur = (int*)take(NBKT * 4);
  int* cbase = (int*)take(NBKT * 4);
  uint2* pairs = (uint2*)take((size_t)NBKT * BCAP * 8);
  int* col = (int*)take((size_t)NE * 4);
  u16* Wt = (u16*)take((size_t)5 * FD * FD * 2);
  u16* W3t = (u16*)take((size_t)48 * FD * 2);
  u16* xb = (u16*)take((size_t)NN * FD * 2);
  u16* h = (u16*)take((size_t)NN * FD * 2);
  u16* y = (u16*)take((size_t)NN * FD * 2);
  u16* y1 = (u16*)take((size_t)NN * FD * 2);

  hipMemsetAsync(bcur, 0, NBKT * 4, stream);

  binA_kernel<<<PA_BLOCKS, 256, 0, stream>>>(esrc, edst, bcur, pairs);
  scanBkt_kernel<<<1, NBKT, 0, stream>>>(bcur, cbase, rowptr);
  binB_kernel<<<NBKT, 256, 0, stream>>>(bcur, cbase, pairs, rowptr, norm, col);

  convx_kernel<<<2048, 256, 0, stream>>>(x, xb);
  transw_kernel<<<dim3(64, 6), 256, 0, stream>>>(Wconv, fc1_w, fc2_w, fc3_w, Wt, W3t);

  const int GB = (NN + 63) / 64;  // 782

  // conv layer 1
  mfma_gemm<0><<<GB, 256, 0, stream>>>(xb, Wt, nullptr, h, NN);
  agg_bf16<<<(NN + 3) / 4, 256, 0, stream>>>(h, norm, rowptr, col, bconv, nullptr, y1);
  // conv layer 2
  mfma_gemm<0><<<GB, 256, 0, stream>>>(y1, Wt + FD * FD, nullptr, h, NN);
  agg_bf16<<<(NN + 3) / 4, 256, 0, stream>>>(h, norm, rowptr, col, bconv + FD, y1, y);
  // conv layer 3
  mfma_gemm<0><<<GB, 256, 0, stream>>>(y, Wt + 2 * FD * FD, nullptr, h, NN);
  agg_bf16<<<(NN + 3) / 4, 256, 0, stream>>>(h, norm, rowptr, col, bconv + 2 * FD, y1, xb);

  // fused fc1+fc2+fc3+log_softmax
  fc123_kernel<<<GB, 256, 0, stream>>>(xb, Wt + 3 * FD * FD, Wt + 4 * FD * FD, W3t,
                                       fc1_b, fc2_b, fc3_b, (float*)d_out, NN);
}